// Round 2
// 170.277 us; speedup vs baseline: 1.3094x; 1.3094x over previous
//
#include <hip/hip_runtime.h>

// Workspace layout (float offsets)
#define WS_M      0        // Mt[r*100+p] = (w_lin2 @ w_lin1)^T, 10000 floats
#define WS_K      10000    // K[c][a][b][ci][u][v], 2646 floats
#define WS_BETA   12646    // beta[c][a][b], 18 floats
#define WS_W9     12664    // W9[c][ci][dy][dx], 486 floats
#define WS_BT     13150    // beta_tot[c] (interior combined bias), 2 floats
#define WS_INI    16384    // ini[b][c][h][w], 1,638,400 floats
#define WS_UIT    (16384 + 1638400)      // uiL[bc][l][p128] bf16, 2,097,152 ushorts
#define WS_UFT    (16384 + 2*1638400)    // ufL[bc][l][p128] bf16

typedef short bf16x8 __attribute__((ext_vector_type(8)));
typedef float f32x4  __attribute__((ext_vector_type(4)));

__device__ inline ushort f2bf(float f) {   // round-to-nearest-even
    unsigned u = __float_as_uint(f);
    unsigned r = (u + 0x7fffu + ((u >> 16) & 1u)) >> 16;
    return (ushort)r;
}

// ---------------------------------------------------------------------------
// Fused prep. blocks 0..39: Mt (10000 elems x 200 MAC).
//             blocks 40..42: K (882 elems each); block 40 also Beta + Bt.
//             blocks 43..44: W9 (243 elems each), recomputed from raw weights
//             (<=9*64 MAC/elem) so no cross-block dependency on K.
__global__ __launch_bounds__(256) void k_prep(const float* __restrict__ wl1,
                                              const float* __restrict__ wl2,
                                              const float* __restrict__ wc1,
                                              const float* __restrict__ bc1,
                                              const float* __restrict__ wc2,
                                              const float* __restrict__ bc2,
                                              float* __restrict__ ws) {
    int blk = blockIdx.x;
    int t = threadIdx.x;
    if (blk < 40) {
        // M[p][r] = sum_q wl2[p,q]*wl1[q,r]; stored transposed Mt[r*100+p]
        int idx = blk * 256 + t;
        if (idx < 10000) {
            int p = idx / 100, r = idx % 100;
            float s = 0.f;
            for (int q = 0; q < 200; ++q)
                s += wl2[p * 200 + q] * wl1[q * 100 + r];
            ws[WS_M + r * 100 + p] = s;
        }
        return;
    }
    __shared__ float swc1[9408];   // 64*3*49
    __shared__ float swc2[1152];   // 2*64*9
    __shared__ float sBeta[18];
    for (int i = t; i < 9408; i += 256) swc1[i] = wc1[i];
    for (int i = t; i < 1152; i += 256) swc2[i] = wc2[i];
    __syncthreads();
    if (blk < 43) {
        int base = (blk - 40) * 882;
        for (int ii = t; ii < 882; ii += 256) {
            int idx = base + ii;
            int v = idx % 7; int t1 = idx / 7;
            int u = t1 % 7;  int t2 = t1 / 7;
            int ci = t2 % 3; int t3 = t2 / 3;
            int b = t3 % 3;  int t4 = t3 / 3;
            int a = t4 % 3;  int c = t4 / 3;
            float s = 0.f;
            for (int c64 = 0; c64 < 64; ++c64)
                s += swc2[((c * 64 + c64) * 3 + a) * 3 + b] *
                     swc1[((c64 * 3 + ci) * 7 + u) * 7 + v];
            ws[WS_K + idx] = s;
        }
        if (blk == 40) {
            if (t < 18) {
                int b = t % 3; int a = (t / 3) % 3; int c = t / 9;
                float s = 0.f;
                for (int c64 = 0; c64 < 64; ++c64)
                    s += swc2[((c * 64 + c64) * 3 + a) * 3 + b] * bc1[c64];
                sBeta[t] = s; ws[WS_BETA + t] = s;
            }
            __syncthreads();
            if (t < 2) {
                float s = bc2[t];
                for (int j2 = 0; j2 < 9; ++j2) s += sBeta[t * 9 + j2];
                ws[WS_BT + t] = s;
            }
        }
    } else {
        // W9[c][ci][dy][dx] = sum_{a,b valid} sum_c64 wc2[c,c64,a,b]*wc1[c64,ci,dy-a,dx-b]
        int idx = (blk - 43) * 243 + t;
        if (t < 243) {
            int dx = idx % 9; int t1 = idx / 9;
            int dy = t1 % 9;  int t2 = t1 / 9;
            int ci = t2 % 3;  int c = t2 / 3;
            float s = 0.f;
            for (int a = 0; a < 3; ++a) {
                int u = dy - a; if (u < 0 || u > 6) continue;
                for (int b = 0; b < 3; ++b) {
                    int v = dx - b; if (v < 0 || v > 6) continue;
                    for (int c64 = 0; c64 < 64; ++c64)
                        s += swc2[((c * 64 + c64) * 3 + a) * 3 + b] *
                             swc1[((c64 * 3 + ci) * 7 + u) * 7 + v];
                }
            }
            ws[WS_W9 + idx] = s;   // layout c*243 + ci*81 + dy*9 + dx
        }
    }
}

// ---------------------------------------------------------------------------
// Fused interior conv + exact border, single launch.
// blocks [0,800): 32x32 tile composite 9x9 conv, LDS 3x40x40 (stride 40:
//   b128 collisions 2-way = free). Edge blocks SKIP ring pixels (predicated
//   scalar stores) so border waves own the ring exclusively -> no WAW race.
// blocks [800,3352): one wave per (border pixel) computing BOTH channels
//   (x-gathers shared between channels; was one wave per (pixel,channel)).
__global__ __launch_bounds__(256) void k_convb(const float* __restrict__ x,
                                               const float* __restrict__ bc2,
                                               const float* __restrict__ ws,
                                               float* __restrict__ ini) {
    __shared__ float sx[3][40][40];
    int bid = blockIdx.x;
    int t = threadIdx.x;
    if (bid < 800) {
        int b = bid / 100, by = (bid / 10) % 10, bx = bid % 10;
        int gh0 = by * 32, gw0 = bx * 32;
        for (int idx = t; idx < 3 * 40 * 40; idx += 256) {
            int ci = idx / 1600;
            int rem = idx - ci * 1600;
            int rr = rem / 40, cc = rem - rr * 40;
            int gh = gh0 - 4 + rr, gw = gw0 - 4 + cc;
            float v = 0.f;
            if ((unsigned)gh < 320u && (unsigned)gw < 320u)
                v = x[(b * 3 + ci) * 102400 + gh * 320 + gw];
            sx[ci][rr][cc] = v;
        }
        __syncthreads();
        const float* W9g = ws + WS_W9;   // wave-uniform -> s_load
        const float* Btg = ws + WS_BT;
        int r = t >> 3, cg = t & 7;
        int h = gh0 + r, w0c = gw0 + cg * 4;
        float acc0[4], acc1[4];
        float bt0 = Btg[0], bt1 = Btg[1];
        #pragma unroll
        for (int j = 0; j < 4; ++j) { acc0[j] = bt0; acc1[j] = bt1; }
        #pragma unroll
        for (int ci = 0; ci < 3; ++ci) {
            #pragma unroll
            for (int dy = 0; dy < 9; ++dy) {
                const float* xr = &sx[ci][r + dy][cg * 4];
                float4 xa = *(const float4*)(xr);
                float4 xb = *(const float4*)(xr + 4);
                float4 xc = *(const float4*)(xr + 8);
                float xv[12] = {xa.x, xa.y, xa.z, xa.w,
                                xb.x, xb.y, xb.z, xb.w,
                                xc.x, xc.y, xc.z, xc.w};
                #pragma unroll
                for (int dx = 0; dx < 9; ++dx) {
                    float w0t = W9g[ci * 81 + dy * 9 + dx];
                    float w1t = W9g[243 + ci * 81 + dy * 9 + dx];
                    #pragma unroll
                    for (int j = 0; j < 4; ++j) {
                        acc0[j] += w0t * xv[dx + j];
                        acc1[j] += w1t * xv[dx + j];
                    }
                }
            }
        }
        size_t obase = (size_t)(b * 2) * 102400 + h * 320 + w0c;
        bool edge = (by == 0) | (by == 9) | (bx == 0) | (bx == 9);
        if (!edge) {
            *(float4*)&ini[obase] = make_float4(acc0[0], acc0[1], acc0[2], acc0[3]);
            *(float4*)&ini[obase + 102400] = make_float4(acc1[0], acc1[1], acc1[2], acc1[3]);
        } else {
            bool rring = (h == 0) | (h == 319);
            #pragma unroll
            for (int j = 0; j < 4; ++j) {
                int w = w0c + j;
                if (!rring && w != 0 && w != 319) {
                    ini[obase + j] = acc0[j];
                    ini[obase + 102400 + j] = acc1[j];
                }
            }
        }
        return;
    }
    // ---- exact border ring (zero-padded conv3(conv7) semantics via K/Beta)
    int witem = (bid - 800) * 4 + (t >> 6);   // 0..10207 = 8 b * 1276 px
    int lane = t & 63;
    int b = witem / 1276, j = witem % 1276;
    int h, w;
    if (j < 320)      { h = 0;           w = j; }
    else if (j < 640) { h = 319;         w = j - 320; }
    else if (j < 958) { h = 1 + j - 640; w = 0; }
    else              { h = 1 + j - 958; w = 319; }
    const float* K    = ws + WS_K;
    const float* Beta = ws + WS_BETA;
    float acc0 = 0.f, acc1 = 0.f;
    #pragma unroll
    for (int rep = 0; rep < 3; ++rep) {
        int e = lane + rep * 64;
        if (e < 189) {
            int a = e / 63;    int rem  = e - a * 63;
            int bb = rem / 21; int rem2 = rem - bb * 21;
            int ci = rem2 / 7; int u = rem2 - ci * 7;
            int hh0 = h + a - 1;
            int ww0 = w + bb - 1;
            bool abv = ((unsigned)hh0 < 320u) & ((unsigned)ww0 < 320u);
            if (abv && ci == 0 && u == 0) {
                acc0 += Beta[a * 3 + bb];
                acc1 += Beta[9 + a * 3 + bb];
            }
            int hx = hh0 + u - 3;
            if (abv && (unsigned)hx < 320u) {
                const float* Kc = K + (a * 9 + bb * 3 + ci) * 49 + u * 7;  // c=0
                const float* xr = x + (b * 3 + ci) * 102400 + hx * 320;
                #pragma unroll
                for (int v = 0; v < 7; ++v) {
                    int wx = ww0 + v - 3;
                    if ((unsigned)wx < 320u) {
                        float xv = xr[wx];
                        acc0 += Kc[v] * xv;
                        acc1 += Kc[1323 + v] * xv;
                    }
                }
            }
        }
    }
    #pragma unroll
    for (int off = 32; off > 0; off >>= 1) {
        acc0 += __shfl_down(acc0, off, 64);
        acc1 += __shfl_down(acc1, off, 64);
    }
    if (lane == 0) {
        size_t pb = (size_t)(b * 2) * 102400 + h * 320 + w;
        ini[pb] = acc0 + bc2[0];
        ini[pb + 102400] = acc1 + bc2[1];
    }
}

// ---------------------------------------------------------------------------
// Fused trans (both modes + both p-groups in one launch): z = (mode<<1)|pg.
// out bf16, l-major: outL[bc][l][p128] = relu(sum_r M[p][r]*patch[l][r]).
// p 100..127 zero-padded (pg==1 blocks, uint2 stores) for k_att's k=128 MFMA.
#define SPS 68
__global__ __launch_bounds__(256) void k_trans(const float* __restrict__ ini,
                                               const float* __restrict__ x,
                                               const float* __restrict__ wfm,
                                               const float* __restrict__ bfm,
                                               const float* __restrict__ ws,
                                               ushort* __restrict__ uiL,
                                               ushort* __restrict__ ufL) {
    __shared__ float sM[100 * 50];    // sM[r*50 + (p - pg*50)]
    __shared__ float sP[100 * SPS];   // sP[r*SPS + li]
    int bc = blockIdx.x;   // 0..15
    int lg = blockIdx.y;   // 0..15 -> 64 patches (2 patch-rows x 32)
    int zz = blockIdx.z;   // 0..3
    int mode = zz >> 1, pg = zz & 1;
    ushort* outL = mode ? ufL : uiL;
    int t = threadIdx.x;
    const float* Mt = ws + WS_M;
    for (int i = t; i < 5000; i += 256) {
        int r = i / 50, p = i % 50;
        sM[i] = Mt[r * 100 + pg * 50 + p];
    }
    int b = bc >> 1, c = bc & 1;
    int row0 = lg * 20;    // image-row base of this block's strip
    if (mode == 0) {
        for (int e = t; e < 6400; e += 256) {
            int irow = e / 320, col = e % 320;
            int off = (row0 + irow) * 320 + col;
            float val = ini[bc * 102400 + off];
            int li = (irow / 10) * 32 + col / 10;
            int r  = (irow % 10) * 10 + col % 10;
            sP[r * SPS + li] = val;
        }
    } else {
        float wf0 = wfm[c * 3 + 0], wf1 = wfm[c * 3 + 1], wf2 = wfm[c * 3 + 2];
        float bf = bfm[c];
        for (int e = t; e < 6400; e += 256) {
            int irow = e / 320, col = e % 320;
            int off = (row0 + irow) * 320 + col;
            float val = (bf + x[(b * 3 + 0) * 102400 + off] * wf0
                            + x[(b * 3 + 1) * 102400 + off] * wf1
                            + x[(b * 3 + 2) * 102400 + off] * wf2) * 0.25f;
            int li = (irow / 10) * 32 + col / 10;
            int r  = (irow % 10) * 10 + col % 10;
            sP[r * SPS + li] = val;
        }
    }
    if (pg == 1) {   // zero the p-pad [100,128) for this block's 64 l's, 8B stores
        for (int e = t; e < 64 * 7; e += 256) {
            int l = lg * 64 + e / 7, q = e % 7;
            *(uint2*)&outL[((size_t)bc * 1024 + l) * 128 + 100 + q * 4] = make_uint2(0u, 0u);
        }
    }
    __syncthreads();
    if (t < 200) {
        int py = t / 8;        // 0..24 -> p0 = py*2
        int lx = t % 8;        // lo = lx*8
        int p0 = py * 2, lo = lx * 8;
        float acc[2][8];
        #pragma unroll
        for (int i = 0; i < 2; ++i)
            #pragma unroll
            for (int j = 0; j < 8; ++j) acc[i][j] = 0.f;
        for (int r = 0; r < 100; ++r) {
            float2 a  = *(const float2*)&sM[r * 50 + p0];
            float4 b0 = *(const float4*)&sP[r * SPS + lo];
            float4 b1 = *(const float4*)&sP[r * SPS + lo + 4];
            float av[2] = {a.x, a.y};
            float bv[8] = {b0.x, b0.y, b0.z, b0.w, b1.x, b1.y, b1.z, b1.w};
            #pragma unroll
            for (int i = 0; i < 2; ++i)
                #pragma unroll
                for (int j = 0; j < 8; ++j)
                    acc[i][j] += av[i] * bv[j];
        }
        int pbase = pg * 50 + p0;   // even -> 4B-aligned ushort2 store
        #pragma unroll
        for (int j = 0; j < 8; ++j) {
            int l = lg * 64 + lo + j;
            unsigned v0 = f2bf(fmaxf(acc[0][j], 0.f));
            unsigned v1 = f2bf(fmaxf(acc[1][j], 0.f));
            *(unsigned*)&outL[((size_t)bc * 1024 + l) * 128 + pbase] = v0 | (v1 << 16);
        }
    }
}

// ---------------------------------------------------------------------------
// att[bc][l][m] = (1/100) * sum_p ui[l][p]*uf[m][p], bf16 MFMA 16x16x32.
// 128x128 tile/block, 4 waves 2x2, each wave 64x64 = 4x4 mfma tiles.
__global__ __launch_bounds__(256) void k_att(const ushort* __restrict__ ui,
                                             const ushort* __restrict__ uf,
                                             float* __restrict__ out) {
    int bc   = blockIdx.z;
    int row0 = blockIdx.y * 128, col0 = blockIdx.x * 128;
    int wave = threadIdx.x >> 6, lane = threadIdx.x & 63;
    int r0 = row0 + (wave >> 1) * 64;
    int c0 = col0 + (wave & 1) * 64;
    int m = lane & 15, quad = lane >> 4;
    const ushort* ub = ui + (size_t)bc * 1024 * 128;
    const ushort* vb = uf + (size_t)bc * 1024 * 128;
    f32x4 acc[4][4];
    #pragma unroll
    for (int i = 0; i < 4; ++i)
        #pragma unroll
        for (int j = 0; j < 4; ++j)
            acc[i][j] = (f32x4){0.f, 0.f, 0.f, 0.f};
    #pragma unroll
    for (int k0 = 0; k0 < 128; k0 += 32) {
        bf16x8 af[4], bfr[4];
        #pragma unroll
        for (int i = 0; i < 4; ++i)
            af[i] = *(const bf16x8*)&ub[(size_t)(r0 + i * 16 + m) * 128 + k0 + quad * 8];
        #pragma unroll
        for (int j = 0; j < 4; ++j)
            bfr[j] = *(const bf16x8*)&vb[(size_t)(c0 + j * 16 + m) * 128 + k0 + quad * 8];
        #pragma unroll
        for (int i = 0; i < 4; ++i)
            #pragma unroll
            for (int j = 0; j < 4; ++j)
                acc[i][j] = __builtin_amdgcn_mfma_f32_16x16x32_bf16(af[i], bfr[j], acc[i][j], 0, 0, 0);
    }
    // C/D: col = lane&15, row = quad*4 + reg (m89/m91-verified)
    #pragma unroll
    for (int i = 0; i < 4; ++i) {
        #pragma unroll
        for (int r = 0; r < 4; ++r) {
            int row = r0 + i * 16 + quad * 4 + r;
            float* o = out + ((size_t)bc * 1024 + row) * 1024;
            #pragma unroll
            for (int j = 0; j < 4; ++j)
                o[c0 + j * 16 + m] = acc[i][j][r] * 0.01f;
        }
    }
}

extern "C" void kernel_launch(void* const* d_in, const int* in_sizes, int n_in,
                              void* d_out, int out_size, void* d_ws, size_t ws_size,
                              hipStream_t stream) {
    const float* x       = (const float*)d_in[0];
    const float* w_conv1 = (const float*)d_in[1];
    const float* b_conv1 = (const float*)d_in[2];
    const float* w_conv2 = (const float*)d_in[3];
    const float* b_conv2 = (const float*)d_in[4];
    const float* w_fm    = (const float*)d_in[5];
    const float* b_fm    = (const float*)d_in[6];
    const float* w_lin1  = (const float*)d_in[7];
    const float* w_lin2  = (const float*)d_in[8];
    float* out = (float*)d_out;
    float* ws  = (float*)d_ws;
    ushort* uiL = (ushort*)(ws + WS_UIT);
    ushort* ufL = (ushort*)(ws + WS_UFT);

    k_prep<<<45, 256, 0, stream>>>(w_lin1, w_lin2, w_conv1, b_conv1, w_conv2, b_conv2, ws);
    k_convb<<<3352, 256, 0, stream>>>(x, b_conv2, ws, ws + WS_INI);
    k_trans<<<dim3(16, 16, 4), 256, 0, stream>>>(ws + WS_INI, x, w_fm, b_fm, ws, uiL, ufL);
    k_att<<<dim3(8, 8, 16), 256, 0, stream>>>(uiL, ufL, out);
}